// Round 7
// baseline (101.614 us; speedup 1.0000x reference)
//
#include <hip/hip_runtime.h>

typedef float f32x16 __attribute__((ext_vector_type(16)));
typedef short s16x8 __attribute__((ext_vector_type(8)));
typedef __bf16 bfx8 __attribute__((ext_vector_type(8)));

#define KN 1024
#define TT 16384
#define NOUT 16382
#define NKT 32   // K' = 2048, tiles of 64

// ws layout: Bpk (64 MiB) at 0; Apk (4 MiB) at 64 MiB; B1 bitmasks alias Bpk start
#define APK_OFF 67108864u

__device__ __forceinline__ unsigned short f2bf(float f) {
  return __builtin_bit_cast(unsigned short, (__bf16)f);
}

__device__ __forceinline__ void gll16(const void* g, void* l) {
  __builtin_amdgcn_global_load_lds(
      (const __attribute__((address_space(1))) void*)g,
      (__attribute__((address_space(3))) void*)l, 16, 0, 0);
}

// ---- kernel 1: adjacency bitmask rows (1024 bits = 32 u32 per node) ----
__global__ __launch_bounds__(256) void k_masks(const float* __restrict__ A,
                                               unsigned* __restrict__ B1) {
  int k = blockIdx.x;
  int tid = threadIdx.x;
  int wv = tid >> 6, lane = tid & 63;
  for (int i = 0; i < 4; ++i) {
    int n = i * 256 + wv * 64 + lane;
    bool bit = (A[(size_t)k * KN + n] > 0.5f) && (n != k);
    unsigned long long m = __ballot(bit);
    if (lane == 0) {
      B1[k * 32 + i * 8 + wv * 2]     = (unsigned)m;
      B1[k * 32 + i * 8 + wv * 2 + 1] = (unsigned)(m >> 32);
    }
  }
}

// ---- kernel 2: interleaved Wc (bf16) packed for 32x32x16 A-fragments ----
// k' = 2n + s (s=0 pairs with X[.,j+1], s=1 with X[.,j])
// u16 idx = (mb*32+kt)*16384 + ks*4096 + koct*2048 + rloc*8 + ii
//   where k' = kt*64 + ks*16 + koct*8 + ii  (A-frag: row=lane&31, koct=lane>>5)
__global__ __launch_bounds__(256) void k_weights(const unsigned* __restrict__ B1,
                                                 const float* __restrict__ alpha,
                                                 const float* __restrict__ beta0,
                                                 const float* __restrict__ beta1,
                                                 unsigned short* __restrict__ Wc) {
  __shared__ unsigned reach[32];
  __shared__ unsigned ex2[32];
  __shared__ unsigned short list[1056];
  __shared__ int nl;
  int k = blockIdx.x, tid = threadIdx.x;
  if (tid == 0) nl = 0;
  if (tid < 32) {
    unsigned r = B1[k * 32 + tid];
    if (tid == (k >> 5)) r |= 1u << (k & 31);  // reach = {k} | N(k)
    reach[tid] = r;
    ex2[tid] = 0;
  }
  __syncthreads();
  for (int m = tid; m < KN; m += 256)
    if ((reach[m >> 5] >> (m & 31)) & 1) {
      int i = atomicAdd(&nl, 1);
      list[i] = (unsigned short)m;
    }
  __syncthreads();
  int n2 = nl;
  for (int i = 0; i < n2; ++i) {
    int m = list[i];
    if (tid < 32) ex2[tid] |= B1[m * 32 + tid];   // union of N(m), m in reach
  }
  __syncthreads();
  if (tid < 32) ex2[tid] &= ~reach[tid];          // distance exactly 2
  __syncthreads();
  int d1 = 0, d2 = 0;
  for (int w = 0; w < 32; ++w) { d1 += __popc(reach[w]); d2 += __popc(ex2[w]); }
  d1 -= 1;  // remove self bit
  float rd1 = 1.0f / fmaxf((float)d1, 1.0f);
  float rd2 = 1.0f / fmaxf((float)d2, 1.0f);
  float c00 = beta0[0] * rd1, c01 = beta0[1] * rd1;
  float c10 = beta1[0] * rd2, c11 = beta1[1] * rd2;
  float a0 = alpha[0], a1 = alpha[1];
  int mb = k >> 8, rloc = k & 255;
  for (int q = 0; q < 4; ++q) {
    int n = tid * 4 + q;
    bool in1 = (((reach[n >> 5] >> (n & 31)) & 1) != 0) && (n != k);
    bool in2 = ((ex2[n >> 5] >> (n & 31)) & 1) != 0;
    float v0 = (in1 ? c00 : 0.f) + (in2 ? c10 : 0.f) + (n == k ? a0 : 0.f);
    float v1 = (in1 ? c01 : 0.f) + (in2 ? c11 : 0.f) + (n == k ? a1 : 0.f);
    int kt = n >> 5, ks = (n >> 3) & 3, koct = (n >> 2) & 1, ii = (n & 3) * 2;
    size_t idx = ((size_t)(mb * 32 + kt)) * 16384 + ks * 4096 + koct * 2048 +
                 rloc * 8 + ii;
    unsigned pair = (unsigned)f2bf(v0) | ((unsigned)f2bf(v1) << 16);
    *reinterpret_cast<unsigned*>(Wc + idx) = pair;
  }
}

// ---- kernel 3: X (f32 K x T) -> bf16 X2 packed B-tiles (32x32x16 layout) ----
// u16 idx = G*8 .. G*8+7; G = (((jb*32+kt)*4+ks)*2+koct)*256 + col
__global__ __launch_bounds__(256) void k_pack_x2(const float* __restrict__ X,
                                                 unsigned short* __restrict__ Bpk) {
  int G = blockIdx.x * 256 + threadIdx.x;   // 0 .. 4,194,303
  int col  = G & 255;
  int koct = (G >> 8) & 1;
  int ks   = (G >> 9) & 3;
  int kt   = (G >> 11) & 31;
  int jb   = G >> 16;                        // 0..63
  int j    = jb * 256 + col;
  int mbase = kt * 32 + ks * 8 + koct * 4;
  unsigned v[4];
#pragma unroll
  for (int p = 0; p < 4; ++p) {
    int m = mbase + p;
    int j1 = j + 1;
    float f0 = (j1 < TT) ? X[(size_t)m * TT + j1] : 0.0f;  // s=0 (even ii)
    float f1 = X[(size_t)m * TT + j];                      // s=1 (odd ii)
    v[p] = (unsigned)f2bf(f0) | ((unsigned)f2bf(f1) << 16);
  }
  uint4 w; w.x = v[0]; w.y = v[1]; w.z = v[2]; w.w = v[3];
  *reinterpret_cast<uint4*>(Bpk + (size_t)G * 8) = w;
}

// ---- kernel 4: 256x256 GEMM, 32x32x16 MFMA, R6 sync skeleton ----
// 8 waves (2M x 4N), wave tile 128x64 (4x2 frags of 32x32), 4 phases/K-tile,
// frag double-buffer, vmcnt(4)+barrier at end of p1/p3.
__global__ __launch_bounds__(512, 2) void k_gemm(const char* __restrict__ Apk,
                                                 const char* __restrict__ Bpk,
                                                 float* __restrict__ Y) {
  __shared__ char lds[131072];  // 2 buf x { A 32K (ks0..3) | B 32K (ks0..3) }
  int bid = blockIdx.x;
  int swz = (bid & 7) * 32 + (bid >> 3);   // XCD-contiguous work chunks
  int jb = swz >> 2, mb = swz & 3;
  int tid = threadIdx.x;
  int lane = tid & 63, wv = tid >> 6;
  int wm = wv >> 2, wn = wv & 3;           // wave out: rows wm*128, cols wn*64
  int l31 = lane & 31, loct = lane >> 5;
  const char* Asrc = Apk + (size_t)mb * (NKT * 32768);
  const char* Bsrc = Bpk + (size_t)jb * (NKT * 32768);
  int aofs = loct * 4096 + (wm * 128 + l31) * 16;       // + mf*512
  int bofs = 32768 + loct * 4096 + (wn * 64 + l31) * 16; // + nf*512

  f32x16 acc[4][2];
#pragma unroll
  for (int a = 0; a < 4; ++a)
#pragma unroll
    for (int b = 0; b < 2; ++b)
#pragma unroll
      for (int r = 0; r < 16; ++r) acc[a][b][r] = 0.f;

  auto stage_half = [&](int tile, int isB, int qh) {
    char* dst = lds + (tile & 1) * 65536 + isB * 32768 + qh * 16384;
    const char* src = (isB ? Bsrc : Asrc) + ((size_t)(tile & (NKT - 1)) * 2 + qh) * 16384;
    gll16(src + tid * 16, dst + tid * 16);
    gll16(src + (size_t)(tid + 512) * 16, dst + (tid + 512) * 16);
  };

#define READ_F(ad, bd, t, ks)                                                       \
  do {                                                                              \
    const char* base_ = lds + ((t) & 1) * 65536 + (ks) * 8192;                      \
    _Pragma("unroll") for (int mf = 0; mf < 4; ++mf)                                \
      ad[mf] = *(const s16x8*)(base_ + aofs + mf * 512);                            \
    _Pragma("unroll") for (int nf = 0; nf < 2; ++nf)                                \
      bd[nf] = *(const s16x8*)(base_ + bofs + nf * 512);                            \
  } while (0)
#define MFMA8(a_, b_)                                                               \
  do {                                                                              \
    __builtin_amdgcn_s_setprio(1);                                                  \
    _Pragma("unroll") for (int mf = 0; mf < 4; ++mf)                                \
      _Pragma("unroll") for (int nf = 0; nf < 2; ++nf)                              \
        acc[mf][nf] = __builtin_amdgcn_mfma_f32_32x32x16_bf16(                      \
            __builtin_bit_cast(bfx8, a_[mf]), __builtin_bit_cast(bfx8, b_[nf]),     \
            acc[mf][nf], 0, 0, 0);                                                  \
    __builtin_amdgcn_s_setprio(0);                                                  \
  } while (0)

  s16x8 aC[4], aN[4], bC[2], bN[2];

  // prologue: 12 loads; vmcnt(4) drains h0(0)+h1(0), leaves h0(1) in flight
  stage_half(0, 0, 0); stage_half(0, 1, 0);
  stage_half(0, 0, 1); stage_half(0, 1, 1);
  stage_half(1, 0, 0); stage_half(1, 1, 0);
  asm volatile("s_waitcnt vmcnt(4)" ::: "memory");
  __builtin_amdgcn_s_barrier();
  READ_F(aC, bC, 0, 0);

  for (int kt = 0; kt < NKT; ++kt) {
    // p0: MFMA(ks0); prefetch ks1; stage A h1(kt+1)
    READ_F(aN, bN, kt, 1);
    stage_half(kt + 1, 0, 1);
    MFMA8(aC, bC);
    // p1: MFMA(ks1); prefetch ks2; stage B h1(kt+1)
    READ_F(aC, bC, kt, 2);
    stage_half(kt + 1, 1, 1);
    MFMA8(aN, bN);
    asm volatile("s_waitcnt vmcnt(4)" ::: "memory");  // drains h0(kt+1)
    __builtin_amdgcn_s_barrier();
    // p2: MFMA(ks2); prefetch ks3; stage A h0(kt+2)
    READ_F(aN, bN, kt, 3);
    stage_half(kt + 2, 0, 0);
    MFMA8(aC, bC);
    // p3: MFMA(ks3); prefetch ks0(kt+1); stage B h0(kt+2)
    READ_F(aC, bC, kt + 1, 0);
    stage_half(kt + 2, 1, 0);
    MFMA8(aN, bN);
    asm volatile("s_waitcnt vmcnt(4)" ::: "memory");  // drains h1(kt+1)
    __builtin_amdgcn_s_barrier();
  }
  asm volatile("s_waitcnt vmcnt(0)" ::: "memory");

  // epilogue: 32x32 C/D layout: col=lane&31, row=(reg&3)+8*(reg>>2)+4*(lane>>5)
  int c0 = jb * 256 + wn * 64;
  int r0 = mb * 256 + wm * 128 + 4 * loct;
#pragma unroll
  for (int mf = 0; mf < 4; ++mf)
#pragma unroll
    for (int nf = 0; nf < 2; ++nf) {
      int c = c0 + nf * 32 + l31;
      if (c < NOUT) {
        int rb = r0 + mf * 32;
#pragma unroll
        for (int reg = 0; reg < 16; ++reg) {
          int r = rb + (reg & 3) + 8 * (reg >> 2);
          Y[(size_t)r * NOUT + c] = acc[mf][nf][reg];
        }
      }
    }
#undef READ_F
#undef MFMA8
}

extern "C" void kernel_launch(void* const* d_in, const int* in_sizes, int n_in,
                              void* d_out, int out_size, void* d_ws, size_t ws_size,
                              hipStream_t stream) {
  const float* X     = (const float*)d_in[0];
  const float* A     = (const float*)d_in[1];
  const float* alpha = (const float*)d_in[2];
  const float* beta0 = (const float*)d_in[3];
  const float* beta1 = (const float*)d_in[4];
  float* Y = (float*)d_out;
  char* ws = (char*)d_ws;
  char* Bpk = ws;                       // 64 MiB
  char* Apk = ws + APK_OFF;             // 4 MiB
  unsigned* B1 = (unsigned*)ws;         // 128 KiB, aliases Bpk (dead before pack)

  k_masks<<<dim3(1024), dim3(256), 0, stream>>>(A, B1);
  k_weights<<<dim3(1024), dim3(256), 0, stream>>>(B1, alpha, beta0, beta1,
                                                  (unsigned short*)Apk);
  k_pack_x2<<<dim3(16384), dim3(256), 0, stream>>>(X, (unsigned short*)Bpk);
  k_gemm<<<dim3(256), dim3(512), 0, stream>>>(Apk, Bpk, Y);
}